// Round 4
// baseline (233.482 us; speedup 1.0000x reference)
//
#include <hip/hip_runtime.h>

// SetEq4to4: out[n,so,i,j,k,l] = sum over 69 basis ops (A,B) + bias.
// n=2, d=8, so=8, N=32, basis=69.
//
// Pipeline (3 regular launches):
//   KR k_red3 (1024 blk x 512 thr): x -> r012,r013,r023 (plane blocks) and r123
//              (col blocks). Epilogues emit red2 (01)(02)(03)(12)(13).
//              Also zeroes the k_mid ticket/flag counters.
//   KM k_mid  (1090 blk x 256 thr, ticket-gated):
//              first 66 ARRIVING blocks (ticket 0..65) = producers:
//                t<64:  red2_23 (block-local 32-sum over r023) + T2f channel mix
//                t=64,65: red1 from red2 rows + T1f channel mix
//                then __threadfence + release-add to flag.
//              tickets >=66 = consumers (k_mix3 body): preload red3 v[4][8],
//                acquire-spin until flag==66, then U3[b] = mixed red3 +
//                folded T2f/T1f/bias.
//              Deadlock-free under ANY dispatch order: producers are by
//              definition the first blocks that got CU slots.
//   K6 k_final (XCD-chunked swizzle): out = sum_d c68*x + U012+U013+U023+U123

constexpr size_t R3SZ  = 524288;   // per-a: 16 nd * 32768
constexpr size_t R2SZ  = 16384;    // per-b2: 16 nd * 1024
constexpr size_t R1SZ  = 512;      // per-b1: 16 nd * 32  (region reused for sync)
constexpr size_t R3OFF = 0;
constexpr size_t R2OFF = R3OFF + 4 * R3SZ;   // red2: b2 0..5 = (01)(02)(03)(12)(13)(23)
constexpr size_t R1OFF = R2OFF + 6 * R2SZ;   // ints: [0]=ticket, [64]=flag
constexpr size_t T2OFF = R1OFF + 4 * R1SZ;
constexpr size_t T1OFF = T2OFF + 6 * R2SZ;
constexpr size_t U3OFF = T1OFF + 4 * R1SZ;
// total ws floats: U3OFF + 4*R3SZ = 4395008  (~17.6 MiB)

// ---------------- KR: rank-3 reductions + most of red2 ----------------
__global__ __launch_bounds__(512) void k_red3(const float* __restrict__ x,
                                              float* __restrict__ ws) {
    __shared__ float4 cp[32][4][8];   // [j][k-octet][l4] col partials (16 KiB)
    __shared__ float  b012[1024];     // [j][k] row sums (4 KiB)
    __shared__ float4 a2[256];        // park buffer (4 KiB)
    const int bid  = blockIdx.x;
    const int t    = threadIdx.x;
    const int half = t >> 8;          // parity of the loop axis handled by this half
    const int tt   = t & 255;
    const int k    = tt >> 3;         // k index owned by this thread
    const int l4   = tt & 7;          // l-quad owned by this thread

    if (bid == 0 && t == 0) {         // zero k_mid's ticket + flag
        ((int*)(ws + R1OFF))[0]  = 0;
        ((int*)(ws + R1OFF))[64] = 0;
    }

    if (bid < 512) {
        // -------- plane blocks: fixed (nd, i), loop over j --------
        const int i    = bid & 31;
        const int nd   = bid >> 5;
        const int w4   = (t >> 6) & 3;   // which k-octet this wave covers
        const int lane = t & 63;
        const float* xp = x + ((size_t)nd << 20) + ((size_t)i << 15) + k * 32 + l4 * 4;
        float4 acc = {0.f, 0.f, 0.f, 0.f};           // r023[i,k,l] accumulator
        #pragma unroll
        for (int it = 0; it < 16; ++it) {
            const int j = it * 2 + half;
            float4 v = *(const float4*)(xp + j * 1024);
            acc.x += v.x; acc.y += v.y; acc.z += v.z; acc.w += v.w;
            // r012[i,j,k] = sum over l: hsum + butterfly over lane bits 0..2
            float h = v.x + v.y + v.z + v.w;
            h += __shfl_xor(h, 1); h += __shfl_xor(h, 2); h += __shfl_xor(h, 4);
            if (l4 == 0) b012[j * 32 + k] = h;
            // col partials over this wave's 8 k's: butterfly over lane bits 3..5
            v.x += __shfl_xor(v.x, 8);  v.y += __shfl_xor(v.y, 8);
            v.z += __shfl_xor(v.z, 8);  v.w += __shfl_xor(v.w, 8);
            v.x += __shfl_xor(v.x, 16); v.y += __shfl_xor(v.y, 16);
            v.z += __shfl_xor(v.z, 16); v.w += __shfl_xor(v.w, 16);
            v.x += __shfl_xor(v.x, 32); v.y += __shfl_xor(v.y, 32);
            v.z += __shfl_xor(v.z, 32); v.w += __shfl_xor(v.w, 32);
            if (lane < 8) cp[j][w4][lane] = v;
        }
        if (half == 1) a2[tt] = acc;                 // park for r023 combine
        __syncthreads();
        const size_t base = ((size_t)nd << 15) + ((size_t)i << 10);
        // r012 write: [i][j*32+k], 2 floats/thread, fully coalesced
        *(float2*)(ws + R3OFF + base + 2 * t) = *(const float2*)(b012 + 2 * t);
        if (half == 0) {
            // r013[i,j,l]: combine the 4 k-octet partials
            const int j = tt >> 3, lj = tt & 7;
            float4 s0 = cp[j][0][lj], s1 = cp[j][1][lj];
            float4 s2 = cp[j][2][lj], s3 = cp[j][3][lj];
            float4 s;
            s.x = s0.x + s1.x + s2.x + s3.x;
            s.y = s0.y + s1.y + s2.y + s3.y;
            s.z = s0.z + s1.z + s2.z + s3.z;
            s.w = s0.w + s1.w + s2.w + s3.w;
            *(float4*)(ws + R3OFF + R3SZ + base + j * 32 + lj * 4) = s;
            // r023[i,k,l]: merge the two j-parity halves
            float4 b = a2[tt];
            a2[tt] = s;                              // repurpose: a2 (as float[1024]) = r013[j][l]
            acc.x += b.x; acc.y += b.y; acc.z += b.z; acc.w += b.w;
            *(float4*)(ws + R3OFF + 2 * R3SZ + base + k * 32 + l4 * 4) = acc;
        }
        __syncthreads();
        // epilogue 2: red2 (01)(02)(03) for this i
        const size_t r2b = (size_t)nd * 1024 + (size_t)i * 32;
        if (t < 32) {
            // red2_01[i][j=t] = sum_k b012[t*32+k]  (skewed k to avoid bank conflicts)
            float s = 0.f;
            #pragma unroll
            for (int kk = 0; kk < 32; ++kk) s += b012[t * 32 + ((kk + t) & 31)];
            ws[R2OFF + 0 * R2SZ + r2b + t] = s;
        } else if (t < 64) {
            // red2_02[i][k] = sum_j b012[j*32+k]  (bank = k, conflict-free)
            const int kc = t - 32;
            float s = 0.f;
            #pragma unroll
            for (int j = 0; j < 32; ++j) s += b012[j * 32 + kc];
            ws[R2OFF + 1 * R2SZ + r2b + kc] = s;
        } else if (t < 96) {
            // red2_03[i][l] = sum_j r013[i][j][l]  (a2 flat view = [j][l], bank = l)
            const int l = t - 64;
            const float* af = (const float*)a2;
            float s = 0.f;
            #pragma unroll
            for (int j = 0; j < 32; ++j) s += af[j * 32 + l];
            ws[R2OFF + 2 * R2SZ + r2b + l] = s;
        }
    } else {
        // -------- col blocks: fixed (nd, j), loop over i --------
        const int bb = bid - 512;
        const int j  = bb & 31;
        const int nd = bb >> 5;
        const float* xp = x + ((size_t)nd << 20) + (size_t)j * 1024 + (size_t)tt * 4;
        float4 acc = {0.f, 0.f, 0.f, 0.f};
        #pragma unroll
        for (int it = 0; it < 16; ++it) {
            const int i = it * 2 + half;
            float4 v = *(const float4*)(xp + ((size_t)i << 15));
            acc.x += v.x; acc.y += v.y; acc.z += v.z; acc.w += v.w;
        }
        if (half == 1) a2[tt] = acc;
        __syncthreads();
        const size_t r2b = (size_t)nd * 1024 + (size_t)j * 32;
        if (half == 0) {
            float4 b = a2[tt];
            acc.x += b.x; acc.y += b.y; acc.z += b.z; acc.w += b.w;
            *(float4*)(ws + R3OFF + 3 * R3SZ + ((size_t)nd << 15)
                       + ((size_t)j << 10) + tt * 4) = acc;   // r123[j][k][l]
            // red2_12[j][k] = sum_l r123: hsum + butterfly over lane bits 0..2
            float h = acc.x + acc.y + acc.z + acc.w;
            h += __shfl_xor(h, 1); h += __shfl_xor(h, 2); h += __shfl_xor(h, 4);
            if ((t & 7) == 0) ws[R2OFF + 3 * R2SZ + r2b + k] = h;
            // red2_13[j][l] = sum_k r123: butterfly lane bits 3..5, then cross-wave
            float4 c2 = acc;
            c2.x += __shfl_xor(c2.x, 8);  c2.y += __shfl_xor(c2.y, 8);
            c2.z += __shfl_xor(c2.z, 8);  c2.w += __shfl_xor(c2.w, 8);
            c2.x += __shfl_xor(c2.x, 16); c2.y += __shfl_xor(c2.y, 16);
            c2.z += __shfl_xor(c2.z, 16); c2.w += __shfl_xor(c2.w, 16);
            c2.x += __shfl_xor(c2.x, 32); c2.y += __shfl_xor(c2.y, 32);
            c2.z += __shfl_xor(c2.z, 32); c2.w += __shfl_xor(c2.w, 32);
            if ((t & 63) < 8) cp[0][t >> 6][t & 63] = c2;
        }
        __syncthreads();
        if (t < 8) {
            float4 s0 = cp[0][0][t], s1 = cp[0][1][t];
            float4 s2 = cp[0][2][t], s3 = cp[0][3][t];
            float4 s;
            s.x = s0.x + s1.x + s2.x + s3.x;
            s.y = s0.y + s1.y + s2.y + s3.y;
            s.z = s0.z + s1.z + s2.z + s3.z;
            s.w = s0.w + s1.w + s2.w + s3.w;
            *(float4*)(ws + R2OFF + 4 * R2SZ + r2b + t * 4) = s;
        }
    }
}

// ---------------- KM: ticket-gated mixT (producers) + mix3 (consumers) ----------------
__global__ __launch_bounds__(256) void k_mid(const float* __restrict__ coefs,
                                             const float* __restrict__ bias,
                                             float* __restrict__ ws) {
    __shared__ float cs[4416];
    __shared__ float s23[256];    // [d][pql]    (producer T2 role)
    __shared__ float r1[1024];    // [a1][d][p]  (producer T1 role)
    __shared__ int   tk;
    const int tt = threadIdx.x;
    for (int idx = tt; idx < 4416; idx += 256) cs[idx] = coefs[idx];
    int* const ctr  = (int*)(ws + R1OFF);
    int* const flag = ctr + 64;
    if (tt == 0)
        tk = __hip_atomic_fetch_add(ctr, 1, __ATOMIC_RELAXED, __HIP_MEMORY_SCOPE_AGENT);
    __syncthreads();
    const int role = tk;

    if (role < 66) {
        // ======== producer: k_mixT body ========
        if (role < 64) {
            // ---- T2f for (n, pq chunk of 32) ----
            const int n  = role >> 5;
            const int ch = role & 31;
            // phase A: red2_23[d][pql] = sum_i r023[(n8+d)][i][ch*32+pql]
            {
                const int d  = tt >> 5, q0 = tt & 31;
                const float* r023p = ws + R3OFF + 2 * R3SZ
                                     + ((size_t)(n * 8 + d) << 15) + ch * 32 + q0;
                float s = 0.f;
                #pragma unroll
                for (int i = 0; i < 32; ++i) s += r023p[i * 1024];
                s23[d * 32 + q0] = s;
            }
            __syncthreads();
            // phase B: T2f[b2][n,so,pq]
            const int so = tt >> 5, pql = tt & 31;
            const int pq = ch * 32 + pql;
            float r2v[5][8];
            #pragma unroll
            for (int a2 = 0; a2 < 5; ++a2)
                #pragma unroll
                for (int d = 0; d < 8; ++d)
                    r2v[a2][d] = ws[R2OFF + (size_t)a2 * R2SZ
                                    + (size_t)(n * 8 + d) * 1024 + pq];
            #pragma unroll
            for (int b2 = 0; b2 < 6; ++b2) {
                float s = 0.f;
                #pragma unroll
                for (int d = 0; d < 8; ++d) {
                    const int cb = (d * 8 + so) * 69 + 16 + b2;
                    #pragma unroll
                    for (int a2 = 0; a2 < 5; ++a2) s += cs[cb + a2 * 6] * r2v[a2][d];
                    s += cs[cb + 30] * s23[d * 32 + pql];
                }
                ws[T2OFF + (size_t)b2 * R2SZ + (size_t)(n * 8 + so) * 1024 + pq] = s;
            }
        } else {
            // ---- T1f for n = role-64 ----
            const int n = role - 64;
            {
                const int a1 = tt >> 6;          // 0..3
                const int dd = (tt >> 3) & 7;    // 0..7
                const int p0 = (tt & 7) * 4;
                const int src = (a1 == 0) ? 0 : ((a1 == 3) ? 4 : 3);
                const float* r2a = ws + R2OFF + (size_t)src * R2SZ
                                   + (size_t)(n * 8 + dd) * 1024;
                #pragma unroll
                for (int pp = 0; pp < 4; ++pp) {
                    const int p = p0 + pp;
                    float s = 0.f;
                    if (a1 <= 1) { for (int q = 0; q < 32; ++q) s += r2a[p * 32 + q]; }
                    else         { for (int q = 0; q < 32; ++q) s += r2a[q * 32 + p]; }
                    r1[(a1 * 8 + dd) * 32 + p] = s;
                }
            }
            __syncthreads();
            const int so = tt >> 5, p = tt & 31;
            #pragma unroll
            for (int b1 = 0; b1 < 4; ++b1) {
                float s = 0.f;
                #pragma unroll
                for (int a1 = 0; a1 < 4; ++a1)
                    #pragma unroll
                    for (int d = 0; d < 8; ++d)
                        s += cs[(d * 8 + so) * 69 + a1 * 4 + b1]
                             * r1[(a1 * 8 + d) * 32 + p];
                ws[T1OFF + (size_t)b1 * R1SZ + (size_t)(n * 8 + so) * 32 + p] = s;
            }
        }
        __threadfence();                 // each thread's stores to device scope
        __syncthreads();
        if (tt == 0)
            __hip_atomic_fetch_add(flag, 1, __ATOMIC_RELEASE, __HIP_MEMORY_SCOPE_AGENT);
    } else {
        // ======== consumer: k_mix3 body ========
        const int blk = role - 66;            // 0..1023 = n(1) | sop(2) | cb(7)
        const int cb  = blk & 127;
        const int sop = (blk >> 7) & 3;
        const int n   = blk >> 9;
        const int c   = cb * 256 + tt;
        const int p1 = c >> 10, p2 = (c >> 5) & 31, p3 = c & 31;
        // preload red3 fragments (ready since k_red3 completed) BEFORE the gate
        float v[4][8];
        #pragma unroll
        for (int a = 0; a < 4; ++a)
            #pragma unroll
            for (int d = 0; d < 8; ++d)
                v[a][d] = ws[R3OFF + (size_t)a * R3SZ
                             + (size_t)(n * 8 + d) * 32768 + c];
        // acquire-spin until all 66 producers have released
        if (tt == 0) {
            while (__hip_atomic_load(flag, __ATOMIC_ACQUIRE,
                                     __HIP_MEMORY_SCOPE_AGENT) < 66)
                __builtin_amdgcn_s_sleep(8);
        }
        __syncthreads();
        const float* T2 = ws + T2OFF;
        const float* T1 = ws + T1OFF;
        #pragma unroll
        for (int b = 0; b < 4; ++b) {
            #pragma unroll
            for (int so2 = 0; so2 < 2; ++so2) {
                const int so = sop * 2 + so2;
                float s = 0.f;
                #pragma unroll
                for (int a = 0; a < 4; ++a)
                    #pragma unroll
                    for (int d = 0; d < 8; ++d)
                        s += cs[(d * 8 + so) * 69 + 52 + a * 4 + b] * v[a][d];
                const size_t nso = (size_t)(n * 8 + so);
                if (b == 0) {
                    s += T2[0 * R2SZ + nso * 1024 + p1 * 32 + p2];
                    s += T2[1 * R2SZ + nso * 1024 + p1 * 32 + p3];
                    s += T2[3 * R2SZ + nso * 1024 + p2 * 32 + p3];
                    s += T1[0 * R1SZ + nso * 32 + p1];
                    s += T1[1 * R1SZ + nso * 32 + p2];
                    s += T1[2 * R1SZ + nso * 32 + p3];
                    s += bias[so];
                } else if (b == 1) {
                    s += T2[2 * R2SZ + nso * 1024 + p1 * 32 + p3];
                    s += T2[4 * R2SZ + nso * 1024 + p2 * 32 + p3];
                    s += T1[3 * R1SZ + nso * 32 + p3];
                } else if (b == 2) {
                    s += T2[5 * R2SZ + nso * 1024 + p2 * 32 + p3];
                }
                ws[U3OFF + (size_t)b * R3SZ + nso * 32768 + c] = s;
            }
        }
    }
}

// ---------------- K6: final broadcast-add + s=4 channel mix ----------------
__global__ __launch_bounds__(256) void k_final(const float* __restrict__ x,
                                               const float* __restrict__ coefs,
                                               const float* __restrict__ ws,
                                               float* __restrict__ out) {
    __shared__ float c68[64];
    if (threadIdx.x < 64) c68[threadIdx.x] = coefs[threadIdx.x * 69 + 68];
    __syncthreads();
    // XCD-chunked bijective swizzle (2048 % 8 == 0): blocks sharing i (and
    // thus the U023 slab + x panels) land on the same XCD's L2.
    const int rb = blockIdx.x;
    const int b  = ((rb & 7) << 8) | (rb >> 3);
    const int j = b & 31;
    const int i = (b >> 5) & 31;
    const int n = b >> 10;
    const int t = threadIdx.x;
    const int k = t >> 3, lq = t & 7;

    float4 xv[8];
    const float* xb = x + ((size_t)n << 23) + ((size_t)i << 15) + j * 1024 + k * 32 + lq * 4;
    #pragma unroll
    for (int d = 0; d < 8; ++d) xv[d] = *(const float4*)(xb + ((size_t)d << 20));

    const float* U = ws + U3OFF;
    const size_t c012 = (size_t)i * 1024 + j * 32 + k;
    const size_t c013 = (size_t)i * 1024 + j * 32 + lq * 4;
    const size_t c023 = (size_t)i * 1024 + k * 32 + lq * 4;
    const size_t c123 = (size_t)j * 1024 + k * 32 + lq * 4;

    #pragma unroll
    for (int so = 0; so < 8; ++so) {
        const size_t nso = (size_t)(n * 8 + so) << 15;
        const float  u0 = U[0 * R3SZ + nso + c012];
        const float4 u1 = *(const float4*)(U + 1 * R3SZ + nso + c013);
        const float4 u2 = *(const float4*)(U + 2 * R3SZ + nso + c023);
        const float4 u3 = *(const float4*)(U + 3 * R3SZ + nso + c123);
        float4 acc;
        acc.x = u0 + u1.x + u2.x + u3.x;
        acc.y = u0 + u1.y + u2.y + u3.y;
        acc.z = u0 + u1.z + u2.z + u3.z;
        acc.w = u0 + u1.w + u2.w + u3.w;
        #pragma unroll
        for (int d = 0; d < 8; ++d) {
            const float w = c68[d * 8 + so];
            acc.x += w * xv[d].x; acc.y += w * xv[d].y;
            acc.z += w * xv[d].z; acc.w += w * xv[d].w;
        }
        *(float4*)(out + ((size_t)(n * 8 + so) << 20) + ((size_t)i << 15)
                   + j * 1024 + k * 32 + lq * 4) = acc;
    }
}

extern "C" void kernel_launch(void* const* d_in, const int* in_sizes, int n_in,
                              void* d_out, int out_size, void* d_ws, size_t ws_size,
                              hipStream_t stream) {
    const float* x     = (const float*)d_in[0];
    const float* coefs = (const float*)d_in[1];
    const float* bias  = (const float*)d_in[2];
    float* out = (float*)d_out;
    float* ws  = (float*)d_ws;

    hipLaunchKernelGGL(k_red3, dim3(1024), dim3(512), 0, stream, x, ws);
    hipLaunchKernelGGL(k_mid,  dim3(1090), dim3(256), 0, stream, coefs, bias, ws);
    hipLaunchKernelGGL(k_final, dim3(2048), dim3(256), 0, stream, x, coefs, ws, out);
}

// Round 5
// 213.603 us; speedup vs baseline: 1.0931x; 1.0931x over previous
//
#include <hip/hip_runtime.h>

// SetEq4to4: out[n,so,i,j,k,l] = sum over 69 basis ops (A,B) + bias.
// n=2, d=8, so=8, N=32, basis=69.
//
// Pipeline (memset + 3 regular launches, no cooperative / no spin gates):
//   MS hipMemsetAsync: zero red2_23 + red1 accumulation regions (73,728 B).
//   KR k_red3 (1024 blk x 512 thr): x -> r012,r013,r023 (plane blocks) and r123
//              (col blocks). Epilogues emit ALL red2: (01)(02)(03) direct [plane],
//              (12)(13) direct [col], (23) via f32 atomicAdd of register r023
//              [plane]. ALL red1: (0) shuffle-reduce of red2_01 [plane, direct],
//              (1) LDS+shuffle of red2_12 [col, direct], (2) atomic of red2_02
//              [plane], (3) atomic of red2_03 [plane].
//   K5 k_mix3 (1024 blk x 256 thr): per-thread register folds T2f/T1f computed
//              inline from red2/red1 (no T-arrays in memory), then
//              U3[b] = mixed red3 + folds + bias.
//   K6 k_final (XCD-chunked swizzle): out = sum_d c68*x + U012+U013+U023+U123

constexpr size_t R3SZ  = 524288;   // per-a: 16 nd * 32768
constexpr size_t R2SZ  = 16384;    // per-b2: 16 nd * 1024
constexpr size_t R1SZ  = 512;      // per-b1: 16 nd * 32
constexpr size_t R3OFF = 0;
constexpr size_t R2OFF = R3OFF + 4 * R3SZ;   // red2: b2 0..5 = (01)(02)(03)(12)(13)(23)
constexpr size_t R1OFF = R2OFF + 6 * R2SZ;   // red1: b1 0..3 = (0)(1)(2)(3)
constexpr size_t U3OFF = R1OFF + 4 * R1SZ;
// total ws floats: U3OFF + 4*R3SZ = 4297728  (~17.2 MiB)
// zeroed-by-memset region: [R2OFF+5*R2SZ, R1OFF+4*R1SZ) = 18432 floats = 73728 B

// ---------------- KR: rank-3 reductions + ALL red2/red1 ----------------
__global__ __launch_bounds__(512) void k_red3(const float* __restrict__ x,
                                              float* __restrict__ ws) {
    __shared__ float4 cp[32][4][8];   // [j][k-octet][l4] col partials (16 KiB)
    __shared__ float  b012[1024];     // [j][k] row sums (4 KiB)
    __shared__ float4 a2[256];        // park buffer (4 KiB)
    const int bid  = blockIdx.x;
    const int t    = threadIdx.x;
    const int half = t >> 8;          // parity of the loop axis handled by this half
    const int tt   = t & 255;
    const int k    = tt >> 3;         // k index owned by this thread
    const int l4   = tt & 7;          // l-quad owned by this thread

    if (bid < 512) {
        // -------- plane blocks: fixed (nd, i), loop over j --------
        const int i    = bid & 31;
        const int nd   = bid >> 5;
        const int w4   = (t >> 6) & 3;   // which k-octet this wave covers
        const int lane = t & 63;
        const float* xp = x + ((size_t)nd << 20) + ((size_t)i << 15) + k * 32 + l4 * 4;
        float4 acc = {0.f, 0.f, 0.f, 0.f};           // r023[i,k,l] accumulator
        #pragma unroll
        for (int it = 0; it < 16; ++it) {
            const int j = it * 2 + half;
            float4 v = *(const float4*)(xp + j * 1024);
            acc.x += v.x; acc.y += v.y; acc.z += v.z; acc.w += v.w;
            // r012[i,j,k] = sum over l: hsum + butterfly over lane bits 0..2
            float h = v.x + v.y + v.z + v.w;
            h += __shfl_xor(h, 1); h += __shfl_xor(h, 2); h += __shfl_xor(h, 4);
            if (l4 == 0) b012[j * 32 + k] = h;
            // col partials over this wave's 8 k's: butterfly over lane bits 3..5
            v.x += __shfl_xor(v.x, 8);  v.y += __shfl_xor(v.y, 8);
            v.z += __shfl_xor(v.z, 8);  v.w += __shfl_xor(v.w, 8);
            v.x += __shfl_xor(v.x, 16); v.y += __shfl_xor(v.y, 16);
            v.z += __shfl_xor(v.z, 16); v.w += __shfl_xor(v.w, 16);
            v.x += __shfl_xor(v.x, 32); v.y += __shfl_xor(v.y, 32);
            v.z += __shfl_xor(v.z, 32); v.w += __shfl_xor(v.w, 32);
            if (lane < 8) cp[j][w4][lane] = v;
        }
        if (half == 1) a2[tt] = acc;                 // park for r023 combine
        __syncthreads();
        const size_t base = ((size_t)nd << 15) + ((size_t)i << 10);
        // r012 write: [i][j*32+k], 2 floats/thread, fully coalesced
        *(float2*)(ws + R3OFF + base + 2 * t) = *(const float2*)(b012 + 2 * t);
        if (half == 0) {
            // r013[i,j,l]: combine the 4 k-octet partials
            const int j = tt >> 3, lj = tt & 7;
            float4 s0 = cp[j][0][lj], s1 = cp[j][1][lj];
            float4 s2 = cp[j][2][lj], s3 = cp[j][3][lj];
            float4 s;
            s.x = s0.x + s1.x + s2.x + s3.x;
            s.y = s0.y + s1.y + s2.y + s3.y;
            s.z = s0.z + s1.z + s2.z + s3.z;
            s.w = s0.w + s1.w + s2.w + s3.w;
            *(float4*)(ws + R3OFF + R3SZ + base + j * 32 + lj * 4) = s;
            // r023[i,k,l]: merge the two j-parity halves
            float4 b = a2[tt];
            a2[tt] = s;                              // repurpose: a2 (as float[1024]) = r013[j][l]
            acc.x += b.x; acc.y += b.y; acc.z += b.z; acc.w += b.w;
            *(float4*)(ws + R3OFF + 2 * R3SZ + base + k * 32 + l4 * 4) = acc;
            // red2_23[k,l] += r023[i,k,l]  (cross-block i-sum via f32 atomics;
            // region zeroed by the stream-head memset)
            float* r23 = ws + R2OFF + 5 * R2SZ + (size_t)nd * 1024 + k * 32 + l4 * 4;
            atomicAdd(r23 + 0, acc.x); atomicAdd(r23 + 1, acc.y);
            atomicAdd(r23 + 2, acc.z); atomicAdd(r23 + 3, acc.w);
        }
        __syncthreads();
        // epilogue 2: red2 (01)(02)(03) + red1 (0)(2)(3) for this i
        const size_t r2b = (size_t)nd * 1024 + (size_t)i * 32;
        if (t < 32) {
            // red2_01[i][j=t] = sum_k b012[t*32+k]  (skewed k to avoid bank conflicts)
            float s = 0.f;
            #pragma unroll
            for (int kk = 0; kk < 32; ++kk) s += b012[t * 32 + ((kk + t) & 31)];
            ws[R2OFF + 0 * R2SZ + r2b + t] = s;
            // red1_0[i] = sum_j red2_01[i][j]: butterfly over lanes 0..31 (wave 0)
            float r = s;
            r += __shfl_xor(r, 1);  r += __shfl_xor(r, 2);  r += __shfl_xor(r, 4);
            r += __shfl_xor(r, 8);  r += __shfl_xor(r, 16);
            if (t == 0) ws[R1OFF + 0 * R1SZ + (size_t)nd * 32 + i] = r;
        } else if (t < 64) {
            // red2_02[i][k] = sum_j b012[j*32+k]  (bank = k, conflict-free)
            const int kc = t - 32;
            float s = 0.f;
            #pragma unroll
            for (int j = 0; j < 32; ++j) s += b012[j * 32 + kc];
            ws[R2OFF + 1 * R2SZ + r2b + kc] = s;
            // red1_2[k] += red2_02[i][k]  (cross-block i-sum)
            atomicAdd(ws + R1OFF + 2 * R1SZ + (size_t)nd * 32 + kc, s);
        } else if (t < 96) {
            // red2_03[i][l] = sum_j r013[i][j][l]  (a2 flat view = [j][l], bank = l)
            const int l = t - 64;
            const float* af = (const float*)a2;
            float s = 0.f;
            #pragma unroll
            for (int j = 0; j < 32; ++j) s += af[j * 32 + l];
            ws[R2OFF + 2 * R2SZ + r2b + l] = s;
            // red1_3[l] += red2_03[i][l]  (cross-block i-sum)
            atomicAdd(ws + R1OFF + 3 * R1SZ + (size_t)nd * 32 + l, s);
        }
    } else {
        // -------- col blocks: fixed (nd, j), loop over i --------
        const int bb = bid - 512;
        const int j  = bb & 31;
        const int nd = bb >> 5;
        const float* xp = x + ((size_t)nd << 20) + (size_t)j * 1024 + (size_t)tt * 4;
        float4 acc = {0.f, 0.f, 0.f, 0.f};
        #pragma unroll
        for (int it = 0; it < 16; ++it) {
            const int i = it * 2 + half;
            float4 v = *(const float4*)(xp + ((size_t)i << 15));
            acc.x += v.x; acc.y += v.y; acc.z += v.z; acc.w += v.w;
        }
        if (half == 1) a2[tt] = acc;
        __syncthreads();
        const size_t r2b = (size_t)nd * 1024 + (size_t)j * 32;
        if (half == 0) {
            float4 b = a2[tt];
            acc.x += b.x; acc.y += b.y; acc.z += b.z; acc.w += b.w;
            *(float4*)(ws + R3OFF + 3 * R3SZ + ((size_t)nd << 15)
                       + ((size_t)j << 10) + tt * 4) = acc;   // r123[j][k][l]
            // red2_12[j][k] = sum_l r123: hsum + butterfly over lane bits 0..2
            float h = acc.x + acc.y + acc.z + acc.w;
            h += __shfl_xor(h, 1); h += __shfl_xor(h, 2); h += __shfl_xor(h, 4);
            if ((t & 7) == 0) {
                ws[R2OFF + 3 * R2SZ + r2b + k] = h;
                b012[k] = h;                          // park for red1_1 reduce
            }
            // red2_13[j][l] = sum_k r123: butterfly lane bits 3..5, then cross-wave
            float4 c2 = acc;
            c2.x += __shfl_xor(c2.x, 8);  c2.y += __shfl_xor(c2.y, 8);
            c2.z += __shfl_xor(c2.z, 8);  c2.w += __shfl_xor(c2.w, 8);
            c2.x += __shfl_xor(c2.x, 16); c2.y += __shfl_xor(c2.y, 16);
            c2.z += __shfl_xor(c2.z, 16); c2.w += __shfl_xor(c2.w, 16);
            c2.x += __shfl_xor(c2.x, 32); c2.y += __shfl_xor(c2.y, 32);
            c2.z += __shfl_xor(c2.z, 32); c2.w += __shfl_xor(c2.w, 32);
            if ((t & 63) < 8) cp[0][t >> 6][t & 63] = c2;
        }
        __syncthreads();
        if (t < 8) {
            float4 s0 = cp[0][0][t], s1 = cp[0][1][t];
            float4 s2 = cp[0][2][t], s3 = cp[0][3][t];
            float4 s;
            s.x = s0.x + s1.x + s2.x + s3.x;
            s.y = s0.y + s1.y + s2.y + s3.y;
            s.z = s0.z + s1.z + s2.z + s3.z;
            s.w = s0.w + s1.w + s2.w + s3.w;
            *(float4*)(ws + R2OFF + 4 * R2SZ + r2b + t * 4) = s;
        }
        if (t < 32) {
            // red1_1[j] = sum_k red2_12[j][k]: butterfly over lanes 0..31 (wave 0)
            float r = b012[t];
            r += __shfl_xor(r, 1);  r += __shfl_xor(r, 2);  r += __shfl_xor(r, 4);
            r += __shfl_xor(r, 8);  r += __shfl_xor(r, 16);
            if (t == 0) ws[R1OFF + 1 * R1SZ + (size_t)nd * 32 + j] = r;
        }
    }
}

// ---------------- K5: U3[b] = mixed red3 + inline T2f/T1f folds + bias ----------------
__global__ __launch_bounds__(256) void k_mix3(const float* __restrict__ coefs,
                                              const float* __restrict__ bias,
                                              float* __restrict__ ws) {
    __shared__ float cs[4416];
    for (int idx = threadIdx.x; idx < 4416; idx += 256) cs[idx] = coefs[idx];
    __syncthreads();
    const int blk = blockIdx.x;           // 1024 = n(1) | sop(2) | cb(7)
    const int cb  = blk & 127;
    const int sop = (blk >> 7) & 3;
    const int n   = blk >> 9;
    const int c   = cb * 256 + threadIdx.x;
    const int p1 = c >> 10, p2 = (c >> 5) & 31, p3 = c & 31;
    const int idxA = p1 * 32 + p2, idxB = p1 * 32 + p3, idxC = p2 * 32 + p3;

    // T2 folds, per so2: slots {0:(b2=0)@p1p2, 1:(1)@p1p3, 2:(3)@p2p3,
    //                          3:(2)@p1p3, 4:(4)@p2p3, 5:(5)@p2p3}
    float t2f[2][6] = {};
    #pragma unroll
    for (int a2 = 0; a2 < 6; ++a2) {
        #pragma unroll
        for (int d = 0; d < 8; ++d) {
            const float* base = ws + R2OFF + (size_t)a2 * R2SZ
                                + (size_t)(n * 8 + d) * 1024;
            const float vA = base[idxA], vB = base[idxB], vC = base[idxC];
            #pragma unroll
            for (int so2 = 0; so2 < 2; ++so2) {
                const int cc = (d * 8 + sop * 2 + so2) * 69 + 16 + a2 * 6;
                t2f[so2][0] += cs[cc + 0] * vA;
                t2f[so2][1] += cs[cc + 1] * vB;
                t2f[so2][2] += cs[cc + 3] * vC;
                t2f[so2][3] += cs[cc + 2] * vB;
                t2f[so2][4] += cs[cc + 4] * vC;
                t2f[so2][5] += cs[cc + 5] * vC;
            }
        }
    }
    // T1 folds, per so2: slots {0:(b1=0)@p1, 1:(1)@p2, 2:(2)@p3, 3:(3)@p3}
    float t1f[2][4] = {};
    #pragma unroll
    for (int a1 = 0; a1 < 4; ++a1) {
        #pragma unroll
        for (int d = 0; d < 8; ++d) {
            const float* base = ws + R1OFF + (size_t)a1 * R1SZ
                                + (size_t)(n * 8 + d) * 32;
            const float v1 = base[p1], v2 = base[p2], v3 = base[p3];
            #pragma unroll
            for (int so2 = 0; so2 < 2; ++so2) {
                const int cc = (d * 8 + sop * 2 + so2) * 69 + a1 * 4;
                t1f[so2][0] += cs[cc + 0] * v1;
                t1f[so2][1] += cs[cc + 1] * v2;
                t1f[so2][2] += cs[cc + 2] * v3;
                t1f[so2][3] += cs[cc + 3] * v3;
            }
        }
    }

    float v[4][8];
    #pragma unroll
    for (int a = 0; a < 4; ++a)
        #pragma unroll
        for (int d = 0; d < 8; ++d)
            v[a][d] = ws[R3OFF + (size_t)a * R3SZ + (size_t)(n * 8 + d) * 32768 + c];
    #pragma unroll
    for (int b = 0; b < 4; ++b) {
        #pragma unroll
        for (int so2 = 0; so2 < 2; ++so2) {
            const int so = sop * 2 + so2;
            float s = 0.f;
            #pragma unroll
            for (int a = 0; a < 4; ++a)
                #pragma unroll
                for (int d = 0; d < 8; ++d)
                    s += cs[(d * 8 + so) * 69 + 52 + a * 4 + b] * v[a][d];
            if (b == 0) {
                s += t2f[so2][0] + t2f[so2][1] + t2f[so2][2];
                s += t1f[so2][0] + t1f[so2][1] + t1f[so2][2];
                s += bias[so];
            } else if (b == 1) {
                s += t2f[so2][3] + t2f[so2][4] + t1f[so2][3];
            } else if (b == 2) {
                s += t2f[so2][5];
            }
            ws[U3OFF + (size_t)b * R3SZ + (size_t)(n * 8 + so) * 32768 + c] = s;
        }
    }
}

// ---------------- K6: final broadcast-add + s=4 channel mix ----------------
__global__ __launch_bounds__(256) void k_final(const float* __restrict__ x,
                                               const float* __restrict__ coefs,
                                               const float* __restrict__ ws,
                                               float* __restrict__ out) {
    __shared__ float c68[64];
    if (threadIdx.x < 64) c68[threadIdx.x] = coefs[threadIdx.x * 69 + 68];
    __syncthreads();
    // XCD-chunked bijective swizzle (2048 % 8 == 0): blocks sharing i (and
    // thus the U023 slab + x panels) land on the same XCD's L2.
    const int rb = blockIdx.x;
    const int b  = ((rb & 7) << 8) | (rb >> 3);
    const int j = b & 31;
    const int i = (b >> 5) & 31;
    const int n = b >> 10;
    const int t = threadIdx.x;
    const int k = t >> 3, lq = t & 7;

    float4 xv[8];
    const float* xb = x + ((size_t)n << 23) + ((size_t)i << 15) + j * 1024 + k * 32 + lq * 4;
    #pragma unroll
    for (int d = 0; d < 8; ++d) xv[d] = *(const float4*)(xb + ((size_t)d << 20));

    const float* U = ws + U3OFF;
    const size_t c012 = (size_t)i * 1024 + j * 32 + k;
    const size_t c013 = (size_t)i * 1024 + j * 32 + lq * 4;
    const size_t c023 = (size_t)i * 1024 + k * 32 + lq * 4;
    const size_t c123 = (size_t)j * 1024 + k * 32 + lq * 4;

    #pragma unroll
    for (int so = 0; so < 8; ++so) {
        const size_t nso = (size_t)(n * 8 + so) << 15;
        const float  u0 = U[0 * R3SZ + nso + c012];
        const float4 u1 = *(const float4*)(U + 1 * R3SZ + nso + c013);
        const float4 u2 = *(const float4*)(U + 2 * R3SZ + nso + c023);
        const float4 u3 = *(const float4*)(U + 3 * R3SZ + nso + c123);
        float4 acc;
        acc.x = u0 + u1.x + u2.x + u3.x;
        acc.y = u0 + u1.y + u2.y + u3.y;
        acc.z = u0 + u1.z + u2.z + u3.z;
        acc.w = u0 + u1.w + u2.w + u3.w;
        #pragma unroll
        for (int d = 0; d < 8; ++d) {
            const float w = c68[d * 8 + so];
            acc.x += w * xv[d].x; acc.y += w * xv[d].y;
            acc.z += w * xv[d].z; acc.w += w * xv[d].w;
        }
        *(float4*)(out + ((size_t)(n * 8 + so) << 20) + ((size_t)i << 15)
                   + j * 1024 + k * 32 + lq * 4) = acc;
    }
}

extern "C" void kernel_launch(void* const* d_in, const int* in_sizes, int n_in,
                              void* d_out, int out_size, void* d_ws, size_t ws_size,
                              hipStream_t stream) {
    const float* x     = (const float*)d_in[0];
    const float* coefs = (const float*)d_in[1];
    const float* bias  = (const float*)d_in[2];
    float* out = (float*)d_out;
    float* ws  = (float*)d_ws;

    // zero the atomically-accumulated regions: red2_23 (16384 f) + red1 (2048 f)
    hipMemsetAsync((void*)(ws + R2OFF + 5 * R2SZ), 0,
                   (R2SZ + 4 * R1SZ) * sizeof(float), stream);
    hipLaunchKernelGGL(k_red3,  dim3(1024), dim3(512), 0, stream, x, ws);
    hipLaunchKernelGGL(k_mix3,  dim3(1024), dim3(256), 0, stream, coefs, bias, ws);
    hipLaunchKernelGGL(k_final, dim3(2048), dim3(256), 0, stream, x, coefs, ws, out);
}

// Round 6
// 172.142 us; speedup vs baseline: 1.3563x; 1.2408x over previous
//
#include <hip/hip_runtime.h>

// SetEq4to4: out[n,so,i,j,k,l] = sum over 69 basis ops (A,B) + bias.
// n=2, d=8, so=8, N=32, basis=69.
//
// Pipeline (memset + 3 regular launches):
//   MS hipMemsetAsync: zero red2_23 + red1 accumulation regions (73,728 B).
//   KR k_red3 (1024 blk x 512 thr): x -> r012,r013,r023 (plane blocks) and r123
//              (col blocks). Epilogues emit ALL red2 (01)(02)(03) direct,
//              (12)(13) direct, (23) via f32 atomicAdd; ALL red1 (0)(1) direct,
//              (2)(3) via atomicAdd.  [verified R5]
//   KF k_mixF (1024 blk x 256 thr): per-BLOCK cooperative fold of T2f/T1f into
//              LDS (shared, not per-thread recompute -- the R5 mistake), then
//              U3[b] = mixed red3 + LDS folds + bias.
//   K6 k_final (XCD-chunked swizzle): out = sum_d c68*x + U012+U013+U023+U123

constexpr size_t R3SZ  = 524288;   // per-a: 16 nd * 32768
constexpr size_t R2SZ  = 16384;    // per-b2: 16 nd * 1024
constexpr size_t R1SZ  = 512;      // per-b1: 16 nd * 32
constexpr size_t R3OFF = 0;
constexpr size_t R2OFF = R3OFF + 4 * R3SZ;   // red2: b2 0..5 = (01)(02)(03)(12)(13)(23)
constexpr size_t R1OFF = R2OFF + 6 * R2SZ;   // red1: b1 0..3 = (0)(1)(2)(3)
constexpr size_t U3OFF = R1OFF + 4 * R1SZ;
// total ws floats: U3OFF + 4*R3SZ = 4297728  (~17.2 MiB)
// zeroed-by-memset region: [R2OFF+5*R2SZ, R1OFF+4*R1SZ) = 18432 floats = 73728 B

// ---------------- KR: rank-3 reductions + ALL red2/red1 ----------------
__global__ __launch_bounds__(512) void k_red3(const float* __restrict__ x,
                                              float* __restrict__ ws) {
    __shared__ float4 cp[32][4][8];   // [j][k-octet][l4] col partials (16 KiB)
    __shared__ float  b012[1024];     // [j][k] row sums (4 KiB)
    __shared__ float4 a2[256];        // park buffer (4 KiB)
    const int bid  = blockIdx.x;
    const int t    = threadIdx.x;
    const int half = t >> 8;          // parity of the loop axis handled by this half
    const int tt   = t & 255;
    const int k    = tt >> 3;         // k index owned by this thread
    const int l4   = tt & 7;          // l-quad owned by this thread

    if (bid < 512) {
        // -------- plane blocks: fixed (nd, i), loop over j --------
        const int i    = bid & 31;
        const int nd   = bid >> 5;
        const int w4   = (t >> 6) & 3;   // which k-octet this wave covers
        const int lane = t & 63;
        const float* xp = x + ((size_t)nd << 20) + ((size_t)i << 15) + k * 32 + l4 * 4;
        float4 acc = {0.f, 0.f, 0.f, 0.f};           // r023[i,k,l] accumulator
        #pragma unroll
        for (int it = 0; it < 16; ++it) {
            const int j = it * 2 + half;
            float4 v = *(const float4*)(xp + j * 1024);
            acc.x += v.x; acc.y += v.y; acc.z += v.z; acc.w += v.w;
            // r012[i,j,k] = sum over l: hsum + butterfly over lane bits 0..2
            float h = v.x + v.y + v.z + v.w;
            h += __shfl_xor(h, 1); h += __shfl_xor(h, 2); h += __shfl_xor(h, 4);
            if (l4 == 0) b012[j * 32 + k] = h;
            // col partials over this wave's 8 k's: butterfly over lane bits 3..5
            v.x += __shfl_xor(v.x, 8);  v.y += __shfl_xor(v.y, 8);
            v.z += __shfl_xor(v.z, 8);  v.w += __shfl_xor(v.w, 8);
            v.x += __shfl_xor(v.x, 16); v.y += __shfl_xor(v.y, 16);
            v.z += __shfl_xor(v.z, 16); v.w += __shfl_xor(v.w, 16);
            v.x += __shfl_xor(v.x, 32); v.y += __shfl_xor(v.y, 32);
            v.z += __shfl_xor(v.z, 32); v.w += __shfl_xor(v.w, 32);
            if (lane < 8) cp[j][w4][lane] = v;
        }
        if (half == 1) a2[tt] = acc;                 // park for r023 combine
        __syncthreads();
        const size_t base = ((size_t)nd << 15) + ((size_t)i << 10);
        // r012 write: [i][j*32+k], 2 floats/thread, fully coalesced
        *(float2*)(ws + R3OFF + base + 2 * t) = *(const float2*)(b012 + 2 * t);
        if (half == 0) {
            // r013[i,j,l]: combine the 4 k-octet partials
            const int j = tt >> 3, lj = tt & 7;
            float4 s0 = cp[j][0][lj], s1 = cp[j][1][lj];
            float4 s2 = cp[j][2][lj], s3 = cp[j][3][lj];
            float4 s;
            s.x = s0.x + s1.x + s2.x + s3.x;
            s.y = s0.y + s1.y + s2.y + s3.y;
            s.z = s0.z + s1.z + s2.z + s3.z;
            s.w = s0.w + s1.w + s2.w + s3.w;
            *(float4*)(ws + R3OFF + R3SZ + base + j * 32 + lj * 4) = s;
            // r023[i,k,l]: merge the two j-parity halves
            float4 b = a2[tt];
            a2[tt] = s;                              // repurpose: a2 (as float[1024]) = r013[j][l]
            acc.x += b.x; acc.y += b.y; acc.z += b.z; acc.w += b.w;
            *(float4*)(ws + R3OFF + 2 * R3SZ + base + k * 32 + l4 * 4) = acc;
            // red2_23[k,l] += r023[i,k,l]  (cross-block i-sum via f32 atomics;
            // region zeroed by the stream-head memset)
            float* r23 = ws + R2OFF + 5 * R2SZ + (size_t)nd * 1024 + k * 32 + l4 * 4;
            atomicAdd(r23 + 0, acc.x); atomicAdd(r23 + 1, acc.y);
            atomicAdd(r23 + 2, acc.z); atomicAdd(r23 + 3, acc.w);
        }
        __syncthreads();
        // epilogue 2: red2 (01)(02)(03) + red1 (0)(2)(3) for this i
        const size_t r2b = (size_t)nd * 1024 + (size_t)i * 32;
        if (t < 32) {
            // red2_01[i][j=t] = sum_k b012[t*32+k]  (skewed k to avoid bank conflicts)
            float s = 0.f;
            #pragma unroll
            for (int kk = 0; kk < 32; ++kk) s += b012[t * 32 + ((kk + t) & 31)];
            ws[R2OFF + 0 * R2SZ + r2b + t] = s;
            // red1_0[i] = sum_j red2_01[i][j]: butterfly over lanes 0..31 (wave 0)
            float r = s;
            r += __shfl_xor(r, 1);  r += __shfl_xor(r, 2);  r += __shfl_xor(r, 4);
            r += __shfl_xor(r, 8);  r += __shfl_xor(r, 16);
            if (t == 0) ws[R1OFF + 0 * R1SZ + (size_t)nd * 32 + i] = r;
        } else if (t < 64) {
            // red2_02[i][k] = sum_j b012[j*32+k]  (bank = k, conflict-free)
            const int kc = t - 32;
            float s = 0.f;
            #pragma unroll
            for (int j = 0; j < 32; ++j) s += b012[j * 32 + kc];
            ws[R2OFF + 1 * R2SZ + r2b + kc] = s;
            // red1_2[k] += red2_02[i][k]  (cross-block i-sum)
            atomicAdd(ws + R1OFF + 2 * R1SZ + (size_t)nd * 32 + kc, s);
        } else if (t < 96) {
            // red2_03[i][l] = sum_j r013[i][j][l]  (a2 flat view = [j][l], bank = l)
            const int l = t - 64;
            const float* af = (const float*)a2;
            float s = 0.f;
            #pragma unroll
            for (int j = 0; j < 32; ++j) s += af[j * 32 + l];
            ws[R2OFF + 2 * R2SZ + r2b + l] = s;
            // red1_3[l] += red2_03[i][l]  (cross-block i-sum)
            atomicAdd(ws + R1OFF + 3 * R1SZ + (size_t)nd * 32 + l, s);
        }
    } else {
        // -------- col blocks: fixed (nd, j), loop over i --------
        const int bb = bid - 512;
        const int j  = bb & 31;
        const int nd = bb >> 5;
        const float* xp = x + ((size_t)nd << 20) + (size_t)j * 1024 + (size_t)tt * 4;
        float4 acc = {0.f, 0.f, 0.f, 0.f};
        #pragma unroll
        for (int it = 0; it < 16; ++it) {
            const int i = it * 2 + half;
            float4 v = *(const float4*)(xp + ((size_t)i << 15));
            acc.x += v.x; acc.y += v.y; acc.z += v.z; acc.w += v.w;
        }
        if (half == 1) a2[tt] = acc;
        __syncthreads();
        const size_t r2b = (size_t)nd * 1024 + (size_t)j * 32;
        if (half == 0) {
            float4 b = a2[tt];
            acc.x += b.x; acc.y += b.y; acc.z += b.z; acc.w += b.w;
            *(float4*)(ws + R3OFF + 3 * R3SZ + ((size_t)nd << 15)
                       + ((size_t)j << 10) + tt * 4) = acc;   // r123[j][k][l]
            // red2_12[j][k] = sum_l r123: hsum + butterfly over lane bits 0..2
            float h = acc.x + acc.y + acc.z + acc.w;
            h += __shfl_xor(h, 1); h += __shfl_xor(h, 2); h += __shfl_xor(h, 4);
            if ((t & 7) == 0) {
                ws[R2OFF + 3 * R2SZ + r2b + k] = h;
                b012[k] = h;                          // park for red1_1 reduce
            }
            // red2_13[j][l] = sum_k r123: butterfly lane bits 3..5, then cross-wave
            float4 c2 = acc;
            c2.x += __shfl_xor(c2.x, 8);  c2.y += __shfl_xor(c2.y, 8);
            c2.z += __shfl_xor(c2.z, 8);  c2.w += __shfl_xor(c2.w, 8);
            c2.x += __shfl_xor(c2.x, 16); c2.y += __shfl_xor(c2.y, 16);
            c2.z += __shfl_xor(c2.z, 16); c2.w += __shfl_xor(c2.w, 16);
            c2.x += __shfl_xor(c2.x, 32); c2.y += __shfl_xor(c2.y, 32);
            c2.z += __shfl_xor(c2.z, 32); c2.w += __shfl_xor(c2.w, 32);
            if ((t & 63) < 8) cp[0][t >> 6][t & 63] = c2;
        }
        __syncthreads();
        if (t < 8) {
            float4 s0 = cp[0][0][t], s1 = cp[0][1][t];
            float4 s2 = cp[0][2][t], s3 = cp[0][3][t];
            float4 s;
            s.x = s0.x + s1.x + s2.x + s3.x;
            s.y = s0.y + s1.y + s2.y + s3.y;
            s.z = s0.z + s1.z + s2.z + s3.z;
            s.w = s0.w + s1.w + s2.w + s3.w;
            *(float4*)(ws + R2OFF + 4 * R2SZ + r2b + t * 4) = s;
        }
        if (t < 32) {
            // red1_1[j] = sum_k red2_12[j][k]: butterfly over lanes 0..31 (wave 0)
            float r = b012[t];
            r += __shfl_xor(r, 1);  r += __shfl_xor(r, 2);  r += __shfl_xor(r, 4);
            r += __shfl_xor(r, 8);  r += __shfl_xor(r, 16);
            if (t == 0) ws[R1OFF + 1 * R1SZ + (size_t)nd * 32 + j] = r;
        }
    }
}

// ---------------- KF: block-shared T2f/T1f fold in LDS + U3 mix ----------------
// block = n(1) | sop(2) | cb(7); c = cb*256+tt; p1 = cb>>2 (fixed),
// p2 = (cb&3)*8 + (tt>>5), p3 = tt&31.
__global__ __launch_bounds__(256) void k_mixF(const float* __restrict__ coefs,
                                              const float* __restrict__ bias,
                                              float* __restrict__ ws) {
    __shared__ float cs[4416];
    __shared__ float tA[2][8];         // T2f[b2=0] @ p1*32+p2'
    __shared__ float tB[2][2][32];     // T2f[1],[2] @ p1*32+p3
    __shared__ float tC[2][3][8][32];  // T2f[3],[4],[5] @ p2*32+p3
    __shared__ float t1[2][4][32];     // T1f[b1] @ p (all 32)
    const int tt = threadIdx.x;
    for (int idx = tt; idx < 4416; idx += 256) cs[idx] = coefs[idx];
    __syncthreads();
    const int blk = blockIdx.x;           // 1024
    const int cb  = blk & 127;
    const int sop = (blk >> 7) & 3;
    const int n   = blk >> 9;
    const int p1  = cb >> 2;
    const int p2b = (cb & 3) * 8;

    // ---- fold C: all 256 threads, one (p2',p3) each; b2 in {3,4,5} ----
    {
        const int p2p = tt >> 5, p3 = tt & 31;
        const int pq  = (p2b + p2p) * 32 + p3;
        float a6[6] = {0.f, 0.f, 0.f, 0.f, 0.f, 0.f};
        #pragma unroll
        for (int a2 = 0; a2 < 6; ++a2) {
            float rv[8];
            #pragma unroll
            for (int d = 0; d < 8; ++d)
                rv[d] = ws[R2OFF + (size_t)a2 * R2SZ + (size_t)(n * 8 + d) * 1024 + pq];
            #pragma unroll
            for (int d = 0; d < 8; ++d) {
                #pragma unroll
                for (int so2 = 0; so2 < 2; ++so2) {
                    const int cc = (d * 8 + sop * 2 + so2) * 69 + 16 + a2 * 6;
                    a6[so2 * 3 + 0] += cs[cc + 3] * rv[d];
                    a6[so2 * 3 + 1] += cs[cc + 4] * rv[d];
                    a6[so2 * 3 + 2] += cs[cc + 5] * rv[d];
                }
            }
        }
        #pragma unroll
        for (int so2 = 0; so2 < 2; ++so2)
            #pragma unroll
            for (int z = 0; z < 3; ++z)
                tC[so2][z][p2p][p3] = a6[so2 * 3 + z];
    }
    // ---- folds B / A / T1 on disjoint thread ranges ----
    if (tt < 32) {
        // B: b2=1,2 at pq = p1*32+p3
        const int p3 = tt;
        const int pq = p1 * 32 + p3;
        float a4[4] = {0.f, 0.f, 0.f, 0.f};
        #pragma unroll
        for (int a2 = 0; a2 < 6; ++a2) {
            float rv[8];
            #pragma unroll
            for (int d = 0; d < 8; ++d)
                rv[d] = ws[R2OFF + (size_t)a2 * R2SZ + (size_t)(n * 8 + d) * 1024 + pq];
            #pragma unroll
            for (int d = 0; d < 8; ++d)
                #pragma unroll
                for (int so2 = 0; so2 < 2; ++so2) {
                    const int cc = (d * 8 + sop * 2 + so2) * 69 + 16 + a2 * 6;
                    a4[so2 * 2 + 0] += cs[cc + 1] * rv[d];
                    a4[so2 * 2 + 1] += cs[cc + 2] * rv[d];
                }
        }
        tB[0][0][p3] = a4[0]; tB[0][1][p3] = a4[1];
        tB[1][0][p3] = a4[2]; tB[1][1][p3] = a4[3];
    } else if (tt < 40) {
        // A: b2=0 at pq = p1*32 + (p2b + p2')
        const int p2p = tt - 32;
        const int pq  = p1 * 32 + p2b + p2p;
        float a2c[2] = {0.f, 0.f};
        #pragma unroll
        for (int a2 = 0; a2 < 6; ++a2) {
            float rv[8];
            #pragma unroll
            for (int d = 0; d < 8; ++d)
                rv[d] = ws[R2OFF + (size_t)a2 * R2SZ + (size_t)(n * 8 + d) * 1024 + pq];
            #pragma unroll
            for (int d = 0; d < 8; ++d)
                #pragma unroll
                for (int so2 = 0; so2 < 2; ++so2)
                    a2c[so2] += cs[(d * 8 + sop * 2 + so2) * 69 + 16 + a2 * 6] * rv[d];
        }
        tA[0][p2p] = a2c[0]; tA[1][p2p] = a2c[1];
    } else if (tt >= 64 && tt < 96) {
        // T1: all b1 at p = tt-64
        const int p = tt - 64;
        float a8[8] = {0.f, 0.f, 0.f, 0.f, 0.f, 0.f, 0.f, 0.f};
        #pragma unroll
        for (int a1 = 0; a1 < 4; ++a1) {
            float rv[8];
            #pragma unroll
            for (int d = 0; d < 8; ++d)
                rv[d] = ws[R1OFF + (size_t)a1 * R1SZ + (size_t)(n * 8 + d) * 32 + p];
            #pragma unroll
            for (int d = 0; d < 8; ++d)
                #pragma unroll
                for (int so2 = 0; so2 < 2; ++so2) {
                    const int cc = (d * 8 + sop * 2 + so2) * 69 + a1 * 4;
                    a8[so2 * 4 + 0] += cs[cc + 0] * rv[d];
                    a8[so2 * 4 + 1] += cs[cc + 1] * rv[d];
                    a8[so2 * 4 + 2] += cs[cc + 2] * rv[d];
                    a8[so2 * 4 + 3] += cs[cc + 3] * rv[d];
                }
        }
        #pragma unroll
        for (int so2 = 0; so2 < 2; ++so2)
            #pragma unroll
            for (int b1 = 0; b1 < 4; ++b1)
                t1[so2][b1][p] = a8[so2 * 4 + b1];
    }
    __syncthreads();

    // ---- main: U3[b] = mixed red3 + LDS folds + bias ----
    const int c   = cb * 256 + tt;
    const int p2p = tt >> 5, p3 = tt & 31;
    const int p2  = p2b + p2p;
    float v[4][8];
    #pragma unroll
    for (int a = 0; a < 4; ++a)
        #pragma unroll
        for (int d = 0; d < 8; ++d)
            v[a][d] = ws[R3OFF + (size_t)a * R3SZ + (size_t)(n * 8 + d) * 32768 + c];
    #pragma unroll
    for (int b = 0; b < 4; ++b) {
        #pragma unroll
        for (int so2 = 0; so2 < 2; ++so2) {
            const int so = sop * 2 + so2;
            float s = 0.f;
            #pragma unroll
            for (int a = 0; a < 4; ++a)
                #pragma unroll
                for (int d = 0; d < 8; ++d)
                    s += cs[(d * 8 + so) * 69 + 52 + a * 4 + b] * v[a][d];
            if (b == 0) {
                s += tA[so2][p2p] + tB[so2][0][p3] + tC[so2][0][p2p][p3];
                s += t1[so2][0][p1] + t1[so2][1][p2] + t1[so2][2][p3];
                s += bias[so];
            } else if (b == 1) {
                s += tB[so2][1][p3] + tC[so2][1][p2p][p3] + t1[so2][3][p3];
            } else if (b == 2) {
                s += tC[so2][2][p2p][p3];
            }
            ws[U3OFF + (size_t)b * R3SZ + (size_t)(n * 8 + so) * 32768 + c] = s;
        }
    }
}

// ---------------- K6: final broadcast-add + s=4 channel mix ----------------
__global__ __launch_bounds__(256) void k_final(const float* __restrict__ x,
                                               const float* __restrict__ coefs,
                                               const float* __restrict__ ws,
                                               float* __restrict__ out) {
    __shared__ float c68[64];
    if (threadIdx.x < 64) c68[threadIdx.x] = coefs[threadIdx.x * 69 + 68];
    __syncthreads();
    // XCD-chunked bijective swizzle (2048 % 8 == 0): blocks sharing i (and
    // thus the U023 slab + x panels) land on the same XCD's L2.
    const int rb = blockIdx.x;
    const int b  = ((rb & 7) << 8) | (rb >> 3);
    const int j = b & 31;
    const int i = (b >> 5) & 31;
    const int n = b >> 10;
    const int t = threadIdx.x;
    const int k = t >> 3, lq = t & 7;

    float4 xv[8];
    const float* xb = x + ((size_t)n << 23) + ((size_t)i << 15) + j * 1024 + k * 32 + lq * 4;
    #pragma unroll
    for (int d = 0; d < 8; ++d) xv[d] = *(const float4*)(xb + ((size_t)d << 20));

    const float* U = ws + U3OFF;
    const size_t c012 = (size_t)i * 1024 + j * 32 + k;
    const size_t c013 = (size_t)i * 1024 + j * 32 + lq * 4;
    const size_t c023 = (size_t)i * 1024 + k * 32 + lq * 4;
    const size_t c123 = (size_t)j * 1024 + k * 32 + lq * 4;

    #pragma unroll
    for (int so = 0; so < 8; ++so) {
        const size_t nso = (size_t)(n * 8 + so) << 15;
        const float  u0 = U[0 * R3SZ + nso + c012];
        const float4 u1 = *(const float4*)(U + 1 * R3SZ + nso + c013);
        const float4 u2 = *(const float4*)(U + 2 * R3SZ + nso + c023);
        const float4 u3 = *(const float4*)(U + 3 * R3SZ + nso + c123);
        float4 acc;
        acc.x = u0 + u1.x + u2.x + u3.x;
        acc.y = u0 + u1.y + u2.y + u3.y;
        acc.z = u0 + u1.z + u2.z + u3.z;
        acc.w = u0 + u1.w + u2.w + u3.w;
        #pragma unroll
        for (int d = 0; d < 8; ++d) {
            const float w = c68[d * 8 + so];
            acc.x += w * xv[d].x; acc.y += w * xv[d].y;
            acc.z += w * xv[d].z; acc.w += w * xv[d].w;
        }
        *(float4*)(out + ((size_t)(n * 8 + so) << 20) + ((size_t)i << 15)
                   + j * 1024 + k * 32 + lq * 4) = acc;
    }
}

extern "C" void kernel_launch(void* const* d_in, const int* in_sizes, int n_in,
                              void* d_out, int out_size, void* d_ws, size_t ws_size,
                              hipStream_t stream) {
    const float* x     = (const float*)d_in[0];
    const float* coefs = (const float*)d_in[1];
    const float* bias  = (const float*)d_in[2];
    float* out = (float*)d_out;
    float* ws  = (float*)d_ws;

    // zero the atomically-accumulated regions: red2_23 (16384 f) + red1 (2048 f)
    hipMemsetAsync((void*)(ws + R2OFF + 5 * R2SZ), 0,
                   (R2SZ + 4 * R1SZ) * sizeof(float), stream);
    hipLaunchKernelGGL(k_red3,  dim3(1024), dim3(512), 0, stream, x, ws);
    hipLaunchKernelGGL(k_mixF,  dim3(1024), dim3(256), 0, stream, coefs, bias, ws);
    hipLaunchKernelGGL(k_final, dim3(2048), dim3(256), 0, stream, x, coefs, ws, out);
}